// Round 7
// baseline (698.953 us; speedup 1.0000x reference)
//
#include <hip/hip_runtime.h>
#include <math.h>

#define HEADS 4
#define DIM 32
#define FDIM 128  // HEADS*DIM

typedef __attribute__((ext_vector_type(8))) short short8;
typedef __attribute__((ext_vector_type(16))) float float16;

__device__ __forceinline__ unsigned short f2bf(float x) {
  unsigned u = __float_as_uint(x);
  u += 0x7FFFu + ((u >> 16) & 1);   // round-to-nearest-even
  return (unsigned short)(u >> 16);
}
__device__ __forceinline__ float bf2f(unsigned short b) {
  return __uint_as_float(((unsigned)b) << 16);
}

// ---------------- prep: W->bf16 transposed  +  linked-list adjacency ----------------
// WT[(layer*R+r)][n][k] = bf16(W[layer][r][k][n])
// head2[(r*2+sub)*N + d] chain heads (sub = e&1); nxt2[r*E+e] = {next_edge, src}
__global__ void prep_kernel(const float* __restrict__ W1, const float* __restrict__ W2,
                            unsigned short* __restrict__ WT,
                            const int* __restrict__ edges, int* __restrict__ head2,
                            int2* __restrict__ nxt2, int E, int N, int R) {
  int idx = blockIdx.x * 256 + threadIdx.x;
  int NW = 2 * R * FDIM * FDIM;
  if (idx < NW) {
    int lr = idx >> 14;
    int rem = idx & 16383;
    int n = rem >> 7, k = rem & 127;
    const float* W = (lr < R) ? (W1 + (size_t)lr * FDIM * FDIM)
                              : (W2 + (size_t)(lr - R) * FDIM * FDIM);
    WT[idx] = f2bf(W[k * FDIM + n]);
    return;
  }
  int i = idx - NW;
  if (i >= R * E) return;
  int r = i / E, e = i - r * E;
  const int* ed = edges + (size_t)r * 2 * E;
  int s = ed[e], d = ed[E + e];
  int old = atomicExch(&head2[(r * 2 + (e & 1)) * N + d], e);
  nxt2[i] = make_int2(old, s);
}

// ---------------- LDS-staged MFMA matmul ----------------
// feat[(r*4+h)][n][32] = bf16( (A0 [+ A1]) @ W[r]^T ); optional hsum = A0+A1 (fp32).
// Block: 128 rows x 128 cols, 4 waves (one 32-row band each), K=128 in regs from LDS.
__global__ __launch_bounds__(256) void mm_kernel(const float* __restrict__ A0,
    const float* __restrict__ A1, float* __restrict__ hsum,
    const unsigned short* __restrict__ WTl, unsigned short* __restrict__ featb, int N) {
  __shared__ unsigned short sA[128 * 136];   // stride 136: 16B-aligned rows, even banks
  int r = blockIdx.y;
  const unsigned short* WT = WTl + (size_t)r * FDIM * FDIM;
  int row0 = blockIdx.x * 128;
  int t = threadIdx.x;
#pragma unroll
  for (int it = 0; it < 16; ++it) {
    int idx = t * 4 + it * 1024;
    int row = idx >> 7, k = idx & 127;
    int grow = row0 + row;
    float4 v = make_float4(0.f, 0.f, 0.f, 0.f);
    if (grow < N) {
      v = *(const float4*)(A0 + (size_t)grow * FDIM + k);
      if (A1) {
        float4 v1 = *(const float4*)(A1 + (size_t)grow * FDIM + k);
        v.x += v1.x; v.y += v1.y; v.z += v1.z; v.w += v1.w;
        *(float4*)(hsum + (size_t)grow * FDIM + k) = v;
      }
    }
    unsigned short* p = sA + row * 136 + k;
    p[0] = f2bf(v.x); p[1] = f2bf(v.y); p[2] = f2bf(v.z); p[3] = f2bf(v.w);
  }
  __syncthreads();
  int lane = t & 63, w = t >> 6;
  int m = lane & 31, q = lane >> 5;
  float16 acc[4] = {0.f, 0.f, 0.f, 0.f};
#pragma unroll
  for (int kc = 0; kc < 8; ++kc) {
    int ko = kc * 16 + q * 8;
    short8 a = *(const short8*)(sA + (w * 32 + m) * 136 + ko);
#pragma unroll
    for (int nt = 0; nt < 4; ++nt) {
      short8 b = *(const short8*)(WT + (size_t)(nt * 32 + m) * FDIM + ko);
      acc[nt] = __builtin_amdgcn_mfma_f32_32x32x16_bf16(a, b, acc[nt], 0, 0, 0);
    }
  }
#pragma unroll
  for (int nt = 0; nt < 4; ++nt) {   // nt == head (32-col tiles align with heads)
    unsigned short* fb = featb + ((size_t)(r * 4 + nt) * N) * DIM;
#pragma unroll
    for (int reg = 0; reg < 16; ++reg) {
      int rr = (reg & 3) + 8 * (reg >> 2) + 4 * q;   // C-layout (m74/m101)
      int gr = row0 + w * 32 + rr;
      if (gr < N) fb[(size_t)gr * DIM + m] = f2bf(acc[nt][reg]);
    }
  }
}

// ---------------- attention coefficients: el/er [(r*4+h)][N] ----------------
__global__ void coef_kernel(const unsigned short* __restrict__ featb,
                            const float* __restrict__ al_all, const float* __restrict__ ar_all,
                            float* __restrict__ el, float* __restrict__ er, int N) {
  int rh = blockIdx.y;            // r*4 + h
  int r = rh >> 2, hd = rh & 3;
  int node = blockIdx.x * 256 + threadIdx.x;
  if (node >= N) return;
  const uint4* fp = (const uint4*)(featb + ((size_t)rh * N + node) * DIM);
  const float4* a4 = (const float4*)(al_all + r * FDIM + hd * DIM);
  const float4* b4 = (const float4*)(ar_all + r * FDIM + hd * DIM);
  uint4 u[4] = {fp[0], fp[1], fp[2], fp[3]};
  unsigned uu[16] = {u[0].x, u[0].y, u[0].z, u[0].w, u[1].x, u[1].y, u[1].z, u[1].w,
                     u[2].x, u[2].y, u[2].z, u[2].w, u[3].x, u[3].y, u[3].z, u[3].w};
  float sl = 0.f, sr = 0.f;
#pragma unroll
  for (int g = 0; g < 8; ++g) {
    float4 av = a4[g], bv = b4[g];
    float f0 = bf2f((unsigned short)(uu[2 * g] & 0xFFFF));
    float f1 = bf2f((unsigned short)(uu[2 * g] >> 16));
    float f2 = bf2f((unsigned short)(uu[2 * g + 1] & 0xFFFF));
    float f3 = bf2f((unsigned short)(uu[2 * g + 1] >> 16));
    sl += f0 * av.x + f1 * av.y + f2 * av.z + f3 * av.w;
    sr += f0 * bv.x + f1 * bv.y + f2 * bv.z + f3 * bv.w;
  }
  el[(size_t)rh * N + node] = sl;
  er[(size_t)rh * N + node] = sr;
}

// ---------------- aggregation core (XCD-partitioned by (r,h)) ----------------
// blockIdx.x & 7 = group g -> XCD g (round-robin heuristic): group's feat slice
// (3.2MB) + el slice (200KB) stay L2-resident. nxt2 stream is non-temporal.
// Wave: lanes 0-31 = 32 nodes (sub 0), lanes 32-63 = same nodes (sub 1);
// sublists merged via shfl_xor(32).

// layer 1: + bias, ELU; writes h0/h1[n][h*32..] (disjoint slices, no atomics)
__global__ __launch_bounds__(256) void agg1_kernel(const unsigned short* __restrict__ featb,
    const float* __restrict__ el, const float* __restrict__ er,
    const int* __restrict__ head2, const int2* __restrict__ nxt2,
    const float* __restrict__ bias, float* __restrict__ h0, float* __restrict__ h1,
    int N, int E) {
  int g = blockIdx.x & 7;
  int nb = blockIdx.x >> 3;
  int r = g >> 2, hd = g & 3;
  int lane = threadIdx.x & 63, w = threadIdx.x >> 6;
  int node = nb * 128 + w * 32 + (lane & 31);
  int sub = lane >> 5;
  bool vn = node < N;
  const unsigned short* f = featb + (size_t)g * N * DIM;
  const float* elr = el + (size_t)g * N;
  const int2* nx = nxt2 + (size_t)r * E;
  float l = 0.f, a[32];
#pragma unroll
  for (int i = 0; i < 32; ++i) a[i] = 0.f;
  if (vn) {
    float er_h = er[(size_t)g * N + node];
    int e = __builtin_nontemporal_load(head2 + (size_t)(r * 2 + sub) * N + node);
    while (e >= 0) {
      long long pv = __builtin_nontemporal_load((const long long*)(nx + e));
      int en = (int)pv, s = (int)(pv >> 32);
      float ee = elr[s] + er_h;
      ee = ee > 0.f ? ee : 0.2f * ee;        // LeakyReLU
      float p = __expf(ee);                  // no max-sub: pre-activations tame
      const uint4* fp = (const uint4*)(f + (size_t)s * DIM);
      uint4 u0 = fp[0], u1 = fp[1], u2 = fp[2], u3 = fp[3];
      l += p;
      unsigned uu[16] = {u0.x, u0.y, u0.z, u0.w, u1.x, u1.y, u1.z, u1.w,
                         u2.x, u2.y, u2.z, u2.w, u3.x, u3.y, u3.z, u3.w};
#pragma unroll
      for (int j = 0; j < 16; ++j) {
        float f0 = __uint_as_float(uu[j] << 16);
        float f1 = __uint_as_float(uu[j] & 0xFFFF0000u);
        a[2 * j]     = fmaf(p, f0, a[2 * j]);
        a[2 * j + 1] = fmaf(p, f1, a[2 * j + 1]);
      }
      e = en;
    }
  }
  l += __shfl_xor(l, 32);                    // merge sublists
#pragma unroll
  for (int i = 0; i < 32; ++i) a[i] += __shfl_xor(a[i], 32);
  if (sub == 0 && vn) {
    float inv = (l > 0.f) ? 1.f / l : 0.f;
    const float4* b4 = (const float4*)(bias + r * FDIM + hd * DIM);
    float* hr = (r == 0) ? h0 : h1;
    float4* hp = (float4*)(hr + (size_t)node * FDIM + hd * DIM);
#pragma unroll
    for (int gq = 0; gq < 8; ++gq) {
      float4 bv = b4[gq];
      float v0 = a[4 * gq] * inv + bv.x;
      float v1 = a[4 * gq + 1] * inv + bv.y;
      float v2 = a[4 * gq + 2] * inv + bv.z;
      float v3 = a[4 * gq + 3] * inv + bv.w;
      v0 = v0 > 0.f ? v0 : __expf(v0) - 1.f;   // ELU
      v1 = v1 > 0.f ? v1 : __expf(v1) - 1.f;
      v2 = v2 > 0.f ? v2 : __expf(v2) - 1.f;
      v3 = v3 > 0.f ? v3 : __expf(v3) - 1.f;
      hp[gq] = make_float4(v0, v1, v2, v3);
    }
  }
}

// layer 2: writes po[g][n][32] = softmax-weighted sum (no bias/res; done in combine)
__global__ __launch_bounds__(256) void agg2_kernel(const unsigned short* __restrict__ featb,
    const float* __restrict__ el, const float* __restrict__ er,
    const int* __restrict__ head2, const int2* __restrict__ nxt2,
    float* __restrict__ po, int N, int E) {
  int g = blockIdx.x & 7;
  int nb = blockIdx.x >> 3;
  int r = g >> 2;
  int lane = threadIdx.x & 63, w = threadIdx.x >> 6;
  int node = nb * 128 + w * 32 + (lane & 31);
  int sub = lane >> 5;
  bool vn = node < N;
  const unsigned short* f = featb + (size_t)g * N * DIM;
  const float* elr = el + (size_t)g * N;
  const int2* nx = nxt2 + (size_t)r * E;
  float l = 0.f, a[32];
#pragma unroll
  for (int i = 0; i < 32; ++i) a[i] = 0.f;
  if (vn) {
    float er_h = er[(size_t)g * N + node];
    int e = __builtin_nontemporal_load(head2 + (size_t)(r * 2 + sub) * N + node);
    while (e >= 0) {
      long long pv = __builtin_nontemporal_load((const long long*)(nx + e));
      int en = (int)pv, s = (int)(pv >> 32);
      float ee = elr[s] + er_h;
      ee = ee > 0.f ? ee : 0.2f * ee;
      float p = __expf(ee);
      const uint4* fp = (const uint4*)(f + (size_t)s * DIM);
      uint4 u0 = fp[0], u1 = fp[1], u2 = fp[2], u3 = fp[3];
      l += p;
      unsigned uu[16] = {u0.x, u0.y, u0.z, u0.w, u1.x, u1.y, u1.z, u1.w,
                         u2.x, u2.y, u2.z, u2.w, u3.x, u3.y, u3.z, u3.w};
#pragma unroll
      for (int j = 0; j < 16; ++j) {
        float f0 = __uint_as_float(uu[j] << 16);
        float f1 = __uint_as_float(uu[j] & 0xFFFF0000u);
        a[2 * j]     = fmaf(p, f0, a[2 * j]);
        a[2 * j + 1] = fmaf(p, f1, a[2 * j + 1]);
      }
      e = en;
    }
  }
  l += __shfl_xor(l, 32);
#pragma unroll
  for (int i = 0; i < 32; ++i) a[i] += __shfl_xor(a[i], 32);
  if (sub == 0 && vn) {
    float inv = (l > 0.f) ? 1.f / l : 0.f;
    float4* op = (float4*)(po + ((size_t)g * N + node) * DIM);
#pragma unroll
    for (int gq = 0; gq < 8; ++gq)
      op[gq] = make_float4(a[4 * gq] * inv, a[4 * gq + 1] * inv,
                           a[4 * gq + 2] * inv, a[4 * gq + 3] * inv);
  }
}

// ---------------- final combine: out = 0.25*(sum_g po + R*sum_h res + sum_rh b2) ----
__global__ void combine2_kernel(const float* __restrict__ po, const float* __restrict__ hsum,
                                const float* __restrict__ b2, float* __restrict__ out,
                                int N, int R) {
  int idx = blockIdx.x * 256 + threadIdx.x;
  if (idx >= N * 32) return;
  int n = idx >> 5, d = idx & 31;
  float s = 0.f;
#pragma unroll
  for (int g = 0; g < 8; ++g) s += po[((size_t)g * N + n) * DIM + d];
  const float* hs = hsum + (size_t)n * FDIM + d;
  float res = hs[0] + hs[32] + hs[64] + hs[96];
  float cb = 0.f;
  for (int r = 0; r < R; ++r) {
    const float* bp = b2 + r * FDIM + d;
    cb += bp[0] + bp[32] + bp[64] + bp[96];
  }
  out[idx] = 0.25f * (s + (float)R * res + cb);
}

extern "C" void kernel_launch(void* const* d_in, const int* in_sizes, int n_in,
                              void* d_out, int out_size, void* d_ws, size_t ws_size,
                              hipStream_t stream) {
  const float* x   = (const float*)d_in[0];
  const float* W1  = (const float*)d_in[1];
  const float* al1 = (const float*)d_in[2];
  const float* ar1 = (const float*)d_in[3];
  const float* b1  = (const float*)d_in[4];
  const float* W2  = (const float*)d_in[5];
  const float* al2 = (const float*)d_in[6];
  const float* ar2 = (const float*)d_in[7];
  const float* b2  = (const float*)d_in[8];
  const int* edges = (const int*)d_in[9];
  float* out = (float*)d_out;

  const int N = in_sizes[0] / FDIM;          // 50000
  const int R = in_sizes[1] / (FDIM * FDIM); // 2
  const int E = in_sizes[9] / (2 * R);       // 800000

  char* ws = (char*)d_ws;
  size_t off = 0;
  auto alloc = [&](size_t bytes) {
    char* p = ws + off;
    off += (bytes + 255) & ~(size_t)255;
    return p;
  };
  unsigned short* featb = (unsigned short*)alloc((size_t)R * 4 * N * DIM * 2); // 25.6 MB
  unsigned short* WT    = (unsigned short*)alloc((size_t)2 * R * FDIM * FDIM * 2);
  float* el   = (float*)alloc((size_t)R * 4 * N * 4);
  float* er   = (float*)alloc((size_t)R * 4 * N * 4);
  float* h0   = (float*)alloc((size_t)N * FDIM * 4);
  float* h1   = (float*)alloc((size_t)N * FDIM * 4);
  float* hsum = (float*)alloc((size_t)N * FDIM * 4);
  float* po   = (float*)alloc((size_t)8 * N * DIM * 4);   // 51.2 MB
  int* head2  = (int*)alloc((size_t)R * 2 * N * 4);
  int2* nxt2  = (int2*)alloc((size_t)R * E * 8);

  hipMemsetAsync(head2, 0xFF, (size_t)R * 2 * N * 4, stream);

  int NW = 2 * R * FDIM * FDIM;
  prep_kernel<<<(NW + R * E + 255) / 256, 256, 0, stream>>>(
      W1, W2, WT, edges, head2, nxt2, E, N, R);

  dim3 mmgrid((N + 127) / 128, R);
  dim3 cgrid((N + 255) / 256, 4 * R);
  int agrid = ((N + 127) / 128) * 8;

  // ---- layer 1 ----
  mm_kernel<<<mmgrid, 256, 0, stream>>>(x, nullptr, nullptr, WT, featb, N);
  coef_kernel<<<cgrid, 256, 0, stream>>>(featb, al1, ar1, el, er, N);
  agg1_kernel<<<agrid, 256, 0, stream>>>(featb, el, er, head2, nxt2, b1, h0, h1, N, E);

  // ---- layer 2 ----
  mm_kernel<<<mmgrid, 256, 0, stream>>>(h0, h1, hsum, WT + (size_t)R * FDIM * FDIM, featb, N);
  coef_kernel<<<cgrid, 256, 0, stream>>>(featb, al2, ar2, el, er, N);
  agg2_kernel<<<agrid, 256, 0, stream>>>(featb, el, er, head2, nxt2, po, N, E);
  combine2_kernel<<<(N * 32 + 255) / 256, 256, 0, stream>>>(po, hsum, b2, out, N, R);
}

// Round 8
// 434.050 us; speedup vs baseline: 1.6103x; 1.6103x over previous
//
#include <hip/hip_runtime.h>
#include <math.h>

#define HEADS 4
#define DIM 32
#define FDIM 128  // HEADS*DIM

typedef __attribute__((ext_vector_type(8))) short short8;
typedef __attribute__((ext_vector_type(16))) float float16;

__device__ __forceinline__ unsigned short f2bf(float x) {
  unsigned u = __float_as_uint(x);
  u += 0x7FFFu + ((u >> 16) & 1);   // round-to-nearest-even
  return (unsigned short)(u >> 16);
}

// ---------------- prep: W->bf16 transposed  +  linked-list adjacency ----------------
// WT[(layer*R+r)][n][k] = bf16(W[layer][r][k][n])
// head2[(r*N+d)*2 + (e&1)] chain heads; nxt2[r*E+e] = {next_edge, src}
__global__ void prep_kernel(const float* __restrict__ W1, const float* __restrict__ W2,
                            unsigned short* __restrict__ WT,
                            const int* __restrict__ edges, int* __restrict__ head2,
                            int2* __restrict__ nxt2, int E, int N, int R) {
  int idx = blockIdx.x * 256 + threadIdx.x;
  int NW = 2 * R * FDIM * FDIM;
  if (idx < NW) {
    int lr = idx >> 14;
    int rem = idx & 16383;
    int n = rem >> 7, k = rem & 127;
    const float* W = (lr < R) ? (W1 + (size_t)lr * FDIM * FDIM)
                              : (W2 + (size_t)(lr - R) * FDIM * FDIM);
    WT[idx] = f2bf(W[k * FDIM + n]);
    return;
  }
  int i = idx - NW;
  if (i >= R * E) return;
  int r = i / E, e = i - r * E;
  const int* ed = edges + (size_t)r * 2 * E;
  int s = ed[e], d = ed[E + e];
  int old = atomicExch(&head2[(r * N + d) * 2 + (e & 1)], e);
  nxt2[i] = make_int2(old, s);
}

// ---------------- MFMA matmul + fused coef, LDS-tiled epilogue ----------------
// feat[r][n][128] = bf16(A @ W[r]^T'), el/er[r][n][h] fused.
// Block: 128 rows x 128 cols; A staged in LDS (coalesced float4), output tile
// round-trips LDS -> coalesced 16B stores; el/er dotted from LDS tile.
__global__ __launch_bounds__(256) void mm_kernel(const float* __restrict__ A,
    const unsigned short* __restrict__ WTl, const float* __restrict__ al_all,
    const float* __restrict__ ar_all, unsigned short* __restrict__ featb_all,
    float* __restrict__ el_all, float* __restrict__ er_all, int N) {
  __shared__ unsigned short sA[128 * 136];   // 34.8 KB; stride 136 keeps 16B align
  __shared__ float sAl[FDIM], sAr[FDIM];
  int r = blockIdx.y;
  const unsigned short* WT = WTl + (size_t)r * FDIM * FDIM;
  int row0 = blockIdx.x * 128;
  int t = threadIdx.x;
  if (t < FDIM) {
    sAl[t] = al_all[r * FDIM + t];
    sAr[t] = ar_all[r * FDIM + t];
  }
  // stage A (fp32 -> bf16), coalesced float4 reads
#pragma unroll
  for (int it = 0; it < 16; ++it) {
    int idx = t * 4 + it * 1024;
    int row = idx >> 7, k = idx & 127;
    int grow = row0 + row;
    float4 v = make_float4(0.f, 0.f, 0.f, 0.f);
    if (grow < N) v = *(const float4*)(A + (size_t)grow * FDIM + k);
    unsigned short* p = sA + row * 136 + k;
    p[0] = f2bf(v.x); p[1] = f2bf(v.y); p[2] = f2bf(v.z); p[3] = f2bf(v.w);
  }
  __syncthreads();
  int lane = t & 63, w = t >> 6;
  int m = lane & 31, q = lane >> 5;
  float16 acc[4] = {0.f, 0.f, 0.f, 0.f};
#pragma unroll
  for (int kc = 0; kc < 8; ++kc) {
    int ko = kc * 16 + q * 8;
    short8 a = *(const short8*)(sA + (w * 32 + m) * 136 + ko);
#pragma unroll
    for (int nt = 0; nt < 4; ++nt) {
      short8 b = *(const short8*)(WT + (size_t)(nt * 32 + m) * FDIM + ko);
      acc[nt] = __builtin_amdgcn_mfma_f32_32x32x16_bf16(a, b, acc[nt], 0, 0, 0);
    }
  }
  __syncthreads();   // all sA reads done; reuse as output tile
#pragma unroll
  for (int nt = 0; nt < 4; ++nt) {
#pragma unroll
    for (int reg = 0; reg < 16; ++reg) {
      int rr = (reg & 3) + 8 * (reg >> 2) + 4 * q;   // C-layout (m74/m101)
      sA[(w * 32 + rr) * 136 + nt * 32 + m] = f2bf(acc[nt][reg]);
    }
  }
  __syncthreads();
  // coalesced feat store: 16B per thread-iter
  unsigned short* fb = featb_all + (size_t)r * N * FDIM;
#pragma unroll
  for (int it = 0; it < 8; ++it) {
    int idx = (t + it * 256) * 8;       // element index in 128x128 tile
    int row = idx >> 7, k = idx & 127;
    int grow = row0 + row;
    if (grow < N)
      *(uint4*)(fb + (size_t)grow * FDIM + k) = *(const uint4*)(sA + row * 136 + k);
  }
  // fused coef: thread -> (row = t>>1, two heads)
  int rowc = t >> 1, grow = row0 + rowc;
  if (grow < N) {
    float* elr = el_all + (size_t)r * N * 4;
    float* err_ = er_all + (size_t)r * N * 4;
#pragma unroll
    for (int hh = 0; hh < 2; ++hh) {
      int hd = (t & 1) * 2 + hh;
      const unsigned short* rp = sA + rowc * 136 + hd * DIM;
      float sl = 0.f, sr = 0.f;
#pragma unroll
      for (int j = 0; j < DIM; ++j) {
        float fv = __uint_as_float(((unsigned)rp[j]) << 16);
        sl = fmaf(fv, sAl[hd * DIM + j], sl);
        sr = fmaf(fv, sAr[hd * DIM + j], sr);
      }
      elr[(size_t)grow * 4 + hd] = sl;
      err_[(size_t)grow * 4 + hd] = sr;
    }
  }
}

// ---------------- layer-1 aggregation (R6-proven form) ----------------
// 8 threads/node: 4 heads x 2 sublists. Serial over relations; sublists merged via
// shfl_xor(4). No max-subtraction (pre-activations tame, validated R4-R6).
__global__ __launch_bounds__(256) void agg1_kernel(const unsigned short* __restrict__ featb,
    const float* __restrict__ el, const float* __restrict__ er,
    const int* __restrict__ head2, const int2* __restrict__ nxt2,
    const float* __restrict__ bias, float* __restrict__ hout, int N, int E, int R) {
  int t = blockIdx.x * 256 + threadIdx.x;
  int node = t >> 3;
  if (node >= N) return;
  int hd = t & 3, sub = (t >> 2) & 1;
  float tot[32];
#pragma unroll
  for (int i = 0; i < 32; ++i) tot[i] = 0.f;
  for (int r = 0; r < R; ++r) {
    const unsigned short* f = featb + (size_t)r * N * FDIM + hd * DIM;
    const float* elr = el + (size_t)r * N * 4;
    const int2* nx = nxt2 + (size_t)r * E;
    float er_h = er[(size_t)r * N * 4 + node * 4 + hd];
    float l = 0.f, a[32];
#pragma unroll
    for (int i = 0; i < 32; ++i) a[i] = 0.f;
    int e = head2[(r * N + node) * 2 + sub];
    while (e >= 0) {
      int2 pr = nx[e];                       // {next, src}: one scattered line
      int s = pr.y;
      float ee = elr[s * 4 + hd] + er_h;
      ee = ee > 0.f ? ee : 0.2f * ee;        // LeakyReLU
      float p = __expf(ee);
      const uint4* fp = (const uint4*)(f + (size_t)s * FDIM);
      uint4 u0 = fp[0], u1 = fp[1], u2 = fp[2], u3 = fp[3];
      l += p;
      unsigned uu[16] = {u0.x, u0.y, u0.z, u0.w, u1.x, u1.y, u1.z, u1.w,
                         u2.x, u2.y, u2.z, u2.w, u3.x, u3.y, u3.z, u3.w};
#pragma unroll
      for (int j = 0; j < 16; ++j) {
        float f0 = __uint_as_float(uu[j] << 16);
        float f1 = __uint_as_float(uu[j] & 0xFFFF0000u);
        a[2 * j]     = fmaf(p, f0, a[2 * j]);
        a[2 * j + 1] = fmaf(p, f1, a[2 * j + 1]);
      }
      e = pr.x;
    }
    l += __shfl_xor(l, 4);                   // merge sublists
#pragma unroll
    for (int i = 0; i < 32; ++i) a[i] += __shfl_xor(a[i], 4);
    float inv = (l > 0.f) ? 1.f / l : 0.f;
    const float4* b4 = (const float4*)(bias + r * FDIM + hd * DIM);
#pragma unroll
    for (int g = 0; g < 8; ++g) {
      float4 bv = b4[g];
      float v0 = a[4 * g] * inv + bv.x;
      float v1 = a[4 * g + 1] * inv + bv.y;
      float v2 = a[4 * g + 2] * inv + bv.z;
      float v3 = a[4 * g + 3] * inv + bv.w;
      tot[4 * g]     += v0 > 0.f ? v0 : __expf(v0) - 1.f;   // ELU
      tot[4 * g + 1] += v1 > 0.f ? v1 : __expf(v1) - 1.f;
      tot[4 * g + 2] += v2 > 0.f ? v2 : __expf(v2) - 1.f;
      tot[4 * g + 3] += v3 > 0.f ? v3 : __expf(v3) - 1.f;
    }
  }
  if (sub == 0) {
    float4* hp = (float4*)(hout + (size_t)node * FDIM + hd * DIM);
#pragma unroll
    for (int g = 0; g < 8; ++g)
      hp[g] = make_float4(tot[4 * g], tot[4 * g + 1], tot[4 * g + 2], tot[4 * g + 3]);
  }
}

// ---------------- layer-2 aggregation + residual + bias + head-mean ----------------
__global__ __launch_bounds__(256) void agg2_kernel(const unsigned short* __restrict__ featb,
    const float* __restrict__ el, const float* __restrict__ er,
    const int* __restrict__ head2, const int2* __restrict__ nxt2,
    const float* __restrict__ bias, const float* __restrict__ hf,
    float* __restrict__ out, int N, int E, int R) {
  int t = blockIdx.x * 256 + threadIdx.x;
  int node = t >> 3;
  if (node >= N) return;
  int hd = t & 3, sub = (t >> 2) & 1;
  float tot[32];
#pragma unroll
  for (int i = 0; i < 32; ++i) tot[i] = 0.f;
  for (int r = 0; r < R; ++r) {
    const unsigned short* f = featb + (size_t)r * N * FDIM + hd * DIM;
    const float* elr = el + (size_t)r * N * 4;
    const int2* nx = nxt2 + (size_t)r * E;
    float er_h = er[(size_t)r * N * 4 + node * 4 + hd];
    float l = 0.f, a[32];
#pragma unroll
    for (int i = 0; i < 32; ++i) a[i] = 0.f;
    int e = head2[(r * N + node) * 2 + sub];
    while (e >= 0) {
      int2 pr = nx[e];
      int s = pr.y;
      float ee = elr[s * 4 + hd] + er_h;
      ee = ee > 0.f ? ee : 0.2f * ee;
      float p = __expf(ee);
      const uint4* fp = (const uint4*)(f + (size_t)s * FDIM);
      uint4 u0 = fp[0], u1 = fp[1], u2 = fp[2], u3 = fp[3];
      l += p;
      unsigned uu[16] = {u0.x, u0.y, u0.z, u0.w, u1.x, u1.y, u1.z, u1.w,
                         u2.x, u2.y, u2.z, u2.w, u3.x, u3.y, u3.z, u3.w};
#pragma unroll
      for (int j = 0; j < 16; ++j) {
        float f0 = __uint_as_float(uu[j] << 16);
        float f1 = __uint_as_float(uu[j] & 0xFFFF0000u);
        a[2 * j]     = fmaf(p, f0, a[2 * j]);
        a[2 * j + 1] = fmaf(p, f1, a[2 * j + 1]);
      }
      e = pr.x;
    }
    l += __shfl_xor(l, 4);
#pragma unroll
    for (int i = 0; i < 32; ++i) a[i] += __shfl_xor(a[i], 4);
    float inv = (l > 0.f) ? 1.f / l : 0.f;
    const float4* b4 = (const float4*)(bias + r * FDIM + hd * DIM);
#pragma unroll
    for (int g = 0; g < 8; ++g) {
      float4 bv = b4[g];
      tot[4 * g]     += a[4 * g] * inv + bv.x;
      tot[4 * g + 1] += a[4 * g + 1] * inv + bv.y;
      tot[4 * g + 2] += a[4 * g + 2] * inv + bv.z;
      tot[4 * g + 3] += a[4 * g + 3] * inv + bv.w;
    }
  }
  // residual added R times (once per relation in the reference)
  {
    const float4* rv4 = (const float4*)(hf + (size_t)node * FDIM + hd * DIM);
#pragma unroll
    for (int g = 0; g < 8; ++g) {
      float4 rv = rv4[g];
      tot[4 * g]     += R * rv.x;
      tot[4 * g + 1] += R * rv.y;
      tot[4 * g + 2] += R * rv.z;
      tot[4 * g + 3] += R * rv.w;
    }
  }
  // head-mean: butterfly over the 4 head lanes
#pragma unroll
  for (int i = 0; i < 32; ++i) {
    float v = tot[i];
    v += __shfl_xor(v, 1);
    v += __shfl_xor(v, 2);
    tot[i] = v * 0.25f;
  }
  if (sub == 0) {   // lane hd stores dims [hd*8, hd*8+8)
    float4* op = (float4*)(out + (size_t)node * 32 + hd * 8);
    op[0] = make_float4(tot[hd * 8], tot[hd * 8 + 1], tot[hd * 8 + 2], tot[hd * 8 + 3]);
    op[1] = make_float4(tot[hd * 8 + 4], tot[hd * 8 + 5], tot[hd * 8 + 6], tot[hd * 8 + 7]);
  }
}

extern "C" void kernel_launch(void* const* d_in, const int* in_sizes, int n_in,
                              void* d_out, int out_size, void* d_ws, size_t ws_size,
                              hipStream_t stream) {
  const float* x   = (const float*)d_in[0];
  const float* W1  = (const float*)d_in[1];
  const float* al1 = (const float*)d_in[2];
  const float* ar1 = (const float*)d_in[3];
  const float* b1  = (const float*)d_in[4];
  const float* W2  = (const float*)d_in[5];
  const float* al2 = (const float*)d_in[6];
  const float* ar2 = (const float*)d_in[7];
  const float* b2  = (const float*)d_in[8];
  const int* edges = (const int*)d_in[9];
  float* out = (float*)d_out;

  const int N = in_sizes[0] / FDIM;          // 50000
  const int R = in_sizes[1] / (FDIM * FDIM); // 2
  const int E = in_sizes[9] / (2 * R);       // 800000

  char* ws = (char*)d_ws;
  size_t off = 0;
  auto alloc = [&](size_t bytes) {
    char* p = ws + off;
    off += (bytes + 255) & ~(size_t)255;
    return p;
  };
  unsigned short* featb = (unsigned short*)alloc((size_t)R * N * FDIM * 2);  // 25.6 MB
  unsigned short* WT    = (unsigned short*)alloc((size_t)2 * R * FDIM * FDIM * 2);
  float* el = (float*)alloc((size_t)R * N * 4 * 4);
  float* er = (float*)alloc((size_t)R * N * 4 * 4);
  float* h  = (float*)alloc((size_t)N * FDIM * 4);
  int* head2 = (int*)alloc((size_t)R * N * 2 * 4);
  int2* nxt2 = (int2*)alloc((size_t)R * E * 8);

  hipMemsetAsync(head2, 0xFF, (size_t)R * N * 2 * 4, stream);

  int NW = 2 * R * FDIM * FDIM;
  prep_kernel<<<(NW + R * E + 255) / 256, 256, 0, stream>>>(
      W1, W2, WT, edges, head2, nxt2, E, N, R);

  dim3 mmgrid((N + 127) / 128, R);
  int agrid = (N * 8 + 255) / 256;

  // ---- layer 1 ----
  mm_kernel<<<mmgrid, 256, 0, stream>>>(x, WT, al1, ar1, featb, el, er, N);
  agg1_kernel<<<agrid, 256, 0, stream>>>(featb, el, er, head2, nxt2, b1, h, N, E, R);

  // ---- layer 2 ----
  mm_kernel<<<mmgrid, 256, 0, stream>>>(h, WT + (size_t)R * FDIM * FDIM, al2, ar2, featb, el, er, N);
  agg2_kernel<<<agrid, 256, 0, stream>>>(featb, el, er, head2, nxt2, b2, h, out, N, E, R);
}